// Round 2
// baseline (118.276 us; speedup 1.0000x reference)
//
#include <hip/hip_runtime.h>

// EulerMisorientation3D — fully fused single-kernel version.
//
// Algebra: only the diagonals of g_hat and inv(g) are needed.
//   For a rotation matrix, adj(g) = det(g) * g^T, so diag(inv(g)) = diag(g)
//   (matches jnp.linalg.inv to fp32 rounding; acos sensitivity keeps the
//   resulting error ~1e-5 on the scalar mean, threshold is 4.4e-2).
//   Diagonal entries only need c1*c2, s1*s2, cP:
//     c1*c2 = 0.5*(cos(p1+p2) + cos(p1-p2)),  s1*s2 = 0.5*(cos(p1-p2) - cos(p1+p2))
//   -> 3 hardware cos per matrix, in REVOLUTIONS (args are x0±x2 and 0.5*x1),
//   no range reduction needed.
//
// Reduction: per-block partials in d_ws + device-scope atomic ticket;
// the last block re-reads all partials in fixed order -> deterministic.

#define NTHR 256

__global__ __launch_bounds__(NTHR)
void euler_mis_fused(const float* __restrict__ x, const float* __restrict__ xh,
                     float* __restrict__ partials, unsigned int* __restrict__ ticket,
                     float* __restrict__ out, int nvox, int nblk, float inv_n) {
    const int tid = threadIdx.x;
    const int bid = blockIdx.x;
    const int gid = bid * NTHR + tid;   // float4 index within a plane

    const float4 a0 = reinterpret_cast<const float4*>(x)[gid];
    const float4 a1 = reinterpret_cast<const float4*>(x + (size_t)nvox)[gid];
    const float4 a2 = reinterpret_cast<const float4*>(x + 2 * (size_t)nvox)[gid];
    const float4 b0 = reinterpret_cast<const float4*>(xh)[gid];
    const float4 b1 = reinterpret_cast<const float4*>(xh + (size_t)nvox)[gid];
    const float4 b2 = reinterpret_cast<const float4*>(xh + 2 * (size_t)nvox)[gid];

    const float u0[4] = {a0.x, a0.y, a0.z, a0.w};
    const float u1[4] = {a1.x, a1.y, a1.z, a1.w};
    const float u2[4] = {a2.x, a2.y, a2.z, a2.w};
    const float v0[4] = {b0.x, b0.y, b0.z, b0.w};
    const float v1[4] = {b1.x, b1.y, b1.z, b1.w};
    const float v2[4] = {b2.x, b2.y, b2.z, b2.w};

    float acc = 0.f;
    #pragma unroll
    for (int j = 0; j < 4; ++j) {
        // g diag (hw cos takes revolutions)
        const float A  = __builtin_amdgcn_cosf(u0[j] + u2[j]);   // cos(p1+p2)
        const float Bc = __builtin_amdgcn_cosf(u0[j] - u2[j]);   // cos(p1-p2)
        const float cP = __builtin_amdgcn_cosf(0.5f * u1[j]);    // cos(Phi)
        const float p  = 0.5f * (A + Bc);                        // c1*c2
        const float q  = 0.5f * (Bc - A);                        // s1*s2
        const float g00 = fmaf(-q, cP, p);                       // c1c2 - s1s2*cP
        const float g11 = fmaf(p, cP, -q);                       // -s1s2 + c1c2*cP

        // g_hat diag
        const float Ah  = __builtin_amdgcn_cosf(v0[j] + v2[j]);
        const float Bh  = __builtin_amdgcn_cosf(v0[j] - v2[j]);
        const float cPh = __builtin_amdgcn_cosf(0.5f * v1[j]);
        const float ph  = 0.5f * (Ah + Bh);
        const float qh  = 0.5f * (Bh - Ah);
        const float h00 = fmaf(-qh, cPh, ph);
        const float h11 = fmaf(ph, cPh, -qh);

        const float tr = fmaf(h00, g00, fmaf(h11, g11, cPh * cP));
        float arg = 0.5f * (tr - 1.0f);
        arg = fminf(1.0f, fmaxf(-1.0f, arg));
        const float m = acosf(arg);
        acc = fmaf(m, m, acc);
    }

    // wave64 butterfly + cross-wave LDS reduce (4 waves)
    #pragma unroll
    for (int off = 32; off > 0; off >>= 1) acc += __shfl_down(acc, off, 64);
    __shared__ float lds[4];
    __shared__ int is_last_s;
    if ((tid & 63) == 0) lds[tid >> 6] = acc;
    __syncthreads();
    if (tid == 0) {
        const float bsum = lds[0] + lds[1] + lds[2] + lds[3];
        partials[bid] = bsum;
        __threadfence();  // agent-scope release of the partial
        const unsigned prev = __hip_atomic_fetch_add(
            ticket, 1u, __ATOMIC_ACQ_REL, __HIP_MEMORY_SCOPE_AGENT);
        is_last_s = (prev == (unsigned)(nblk - 1)) ? 1 : 0;
    }
    __syncthreads();
    if (!is_last_s) return;

    // Last block: deterministic fixed-order reduction of all partials.
    __threadfence();  // acquire: invalidate caches so partials are fresh
    float s = 0.f;
    for (int i = tid; i < nblk; i += NTHR) s += partials[i];
    #pragma unroll
    for (int off = 32; off > 0; off >>= 1) s += __shfl_down(s, off, 64);
    __syncthreads();
    if ((tid & 63) == 0) lds[tid >> 6] = s;
    __syncthreads();
    if (tid == 0) {
        out[0] = (lds[0] + lds[1] + lds[2] + lds[3]) * inv_n;
        *ticket = 0u;  // self-reset for the next (graph-replayed) call
    }
}

extern "C" void kernel_launch(void* const* d_in, const int* in_sizes, int n_in,
                              void* d_out, int out_size, void* d_ws, size_t ws_size,
                              hipStream_t stream) {
    const float* x  = (const float*)d_in[0];
    const float* xh = (const float*)d_in[1];
    float* out = (float*)d_out;

    const int nvox = in_sizes[0] / 3;          // 128^3 = 2,097,152
    const int nvec = nvox / 4;                 // float4 groups per plane
    const int nblk = (nvec + NTHR - 1) / NTHR; // 2048

    float* partials = (float*)d_ws;
    unsigned int* ticket = (unsigned int*)(partials + nblk);

    // ticket must be 0 at kernel start on every call (ws is poisoned once,
    // not re-poisoned; the kernel also self-resets it, memset is belt+braces).
    hipMemsetAsync(ticket, 0, sizeof(unsigned int), stream);

    euler_mis_fused<<<nblk, NTHR, 0, stream>>>(x, xh, partials, ticket, out,
                                               nvox, nblk, 1.0f / (float)nvox);
}

// Round 3
// 18.245 us; speedup vs baseline: 6.4826x; 6.4826x over previous
//
#include <hip/hip_runtime.h>

// EulerMisorientation3D — two-kernel version (partials + tiny finalize).
//
// Algebra (verified absmax 0.0 in R2): only diagonals of g_hat and inv(g)
// are needed; for a rotation, diag(inv(g)) = diag(g) (adj(g) = det*g^T).
// Diagonals need only c1*c2, s1*s2, cP via product-to-sum:
//   c1*c2 = 0.5*(cos(p1+p2)+cos(p1-p2)),  s1*s2 = 0.5*(cos(p1-p2)-cos(p1+p2))
// Hardware v_cos_f32 takes REVOLUTIONS, so args are x0±x2 and 0.5*x1 directly —
// no range reduction. 3 cos per matrix, 6 per voxel, + 1 acosf.
//
// R2 lesson: NO per-block device-scope fences/atomics on gfx950 — each
// agent-scope release forces an L2 writeback (non-coherent per-XCD L2s),
// 2048 of them cost ~100us. Two plain kernels are far cheaper.

#define NTHR 256

__device__ __forceinline__ float block_reduce(float v, float* lds, int tid) {
    #pragma unroll
    for (int off = 32; off > 0; off >>= 1) v += __shfl_down(v, off, 64);
    if ((tid & 63) == 0) lds[tid >> 6] = v;
    __syncthreads();
    float r = 0.f;
    if (tid == 0) r = lds[0] + lds[1] + lds[2] + lds[3];
    return r;
}

__global__ __launch_bounds__(NTHR)
void euler_mis_partial(const float* __restrict__ x, const float* __restrict__ xh,
                       float* __restrict__ partials, int nvox) {
    const int tid = threadIdx.x;
    const int gid = blockIdx.x * NTHR + tid;   // float4 index within a plane

    const float4 a0 = reinterpret_cast<const float4*>(x)[gid];
    const float4 a1 = reinterpret_cast<const float4*>(x + (size_t)nvox)[gid];
    const float4 a2 = reinterpret_cast<const float4*>(x + 2 * (size_t)nvox)[gid];
    const float4 b0 = reinterpret_cast<const float4*>(xh)[gid];
    const float4 b1 = reinterpret_cast<const float4*>(xh + (size_t)nvox)[gid];
    const float4 b2 = reinterpret_cast<const float4*>(xh + 2 * (size_t)nvox)[gid];

    const float u0[4] = {a0.x, a0.y, a0.z, a0.w};
    const float u1[4] = {a1.x, a1.y, a1.z, a1.w};
    const float u2[4] = {a2.x, a2.y, a2.z, a2.w};
    const float v0[4] = {b0.x, b0.y, b0.z, b0.w};
    const float v1[4] = {b1.x, b1.y, b1.z, b1.w};
    const float v2[4] = {b2.x, b2.y, b2.z, b2.w};

    float acc = 0.f;
    #pragma unroll
    for (int j = 0; j < 4; ++j) {
        // g diag (hw cos takes revolutions)
        const float A  = __builtin_amdgcn_cosf(u0[j] + u2[j]);   // cos(p1+p2)
        const float Bc = __builtin_amdgcn_cosf(u0[j] - u2[j]);   // cos(p1-p2)
        const float cP = __builtin_amdgcn_cosf(0.5f * u1[j]);    // cos(Phi)
        const float p  = 0.5f * (A + Bc);                        // c1*c2
        const float q  = 0.5f * (Bc - A);                        // s1*s2
        const float g00 = fmaf(-q, cP, p);                       // c1c2 - s1s2*cP
        const float g11 = fmaf(p, cP, -q);                       // -s1s2 + c1c2*cP

        // g_hat diag
        const float Ah  = __builtin_amdgcn_cosf(v0[j] + v2[j]);
        const float Bh  = __builtin_amdgcn_cosf(v0[j] - v2[j]);
        const float cPh = __builtin_amdgcn_cosf(0.5f * v1[j]);
        const float ph  = 0.5f * (Ah + Bh);
        const float qh  = 0.5f * (Bh - Ah);
        const float h00 = fmaf(-qh, cPh, ph);
        const float h11 = fmaf(ph, cPh, -qh);

        const float tr = fmaf(h00, g00, fmaf(h11, g11, cPh * cP));
        float arg = 0.5f * (tr - 1.0f);
        arg = fminf(1.0f, fmaxf(-1.0f, arg));
        const float m = acosf(arg);
        acc = fmaf(m, m, acc);
    }

    __shared__ float lds[4];
    const float bsum = block_reduce(acc, lds, tid);
    if (tid == 0) partials[blockIdx.x] = bsum;
}

__global__ __launch_bounds__(NTHR)
void euler_mis_finalize(const float* __restrict__ partials, int nblk,
                        float* __restrict__ out, float inv_n) {
    const int tid = threadIdx.x;
    float s = 0.f;
    for (int i = tid; i < nblk; i += NTHR) s += partials[i];
    __shared__ float lds[4];
    const float tot = block_reduce(s, lds, tid);
    if (tid == 0) out[0] = tot * inv_n;
}

extern "C" void kernel_launch(void* const* d_in, const int* in_sizes, int n_in,
                              void* d_out, int out_size, void* d_ws, size_t ws_size,
                              hipStream_t stream) {
    const float* x  = (const float*)d_in[0];
    const float* xh = (const float*)d_in[1];
    float* out = (float*)d_out;
    float* partials = (float*)d_ws;

    const int nvox = in_sizes[0] / 3;          // 128^3 = 2,097,152
    const int nvec = nvox / 4;                 // float4 groups per plane
    const int nblk = (nvec + NTHR - 1) / NTHR; // 2048

    euler_mis_partial<<<nblk, NTHR, 0, stream>>>(x, xh, partials, nvox);
    euler_mis_finalize<<<1, NTHR, 0, stream>>>(partials, nblk, out, 1.0f / (float)nvox);
}